// Round 3
// baseline (142.415 us; speedup 1.0000x reference)
//
#include <hip/hip_runtime.h>
#include <stdint.h>

// Problem constants
#define NBATCH 1024
#define NQ 300
#define NC 80
#define QC 24000      // NQ * NC floats per batch
#define TOPK 300
#define RSEL 384u     // radix-select target rank (margin over 300 covers sigmoid ties)
#define NT 512        // threads per block
#define SELCAP 512    // candidate buffer
#define NV4 12        // float4 slots per thread (11 full + tail)
#define TAIL4 368     // threads with a valid 12th float4 (6000 - 11*512)

// ---------------------------------------------------------------------------
// pick<NB,ZERO>: given hist[NB] (finalized), find bucket (from the top)
// containing the rem-th largest element and residual count inside it.
// If ZERO, also re-zeroes hist (each thread owns its G buckets; race-free,
// covered by the existing barriers). 3 barriers total.
// ---------------------------------------------------------------------------
template<int NB, bool ZERO>
__device__ __forceinline__ void pick(uint32_t* __restrict__ hist,
                                     uint32_t* __restrict__ part,
                                     uint32_t* __restrict__ gsufx,
                                     uint32_t* __restrict__ misc,
                                     int tid, uint32_t rem,
                                     uint32_t* bucket_out, uint32_t* rem_out) {
    constexpr int G = (NB >= NT) ? (NB / NT) : 1;
    const int base = tid * G;
    uint32_t h[G];
    uint32_t s = 0;
    if (base < NB) {
#pragma unroll
        for (int u = 0; u < G; ++u) { h[u] = hist[base + u]; s += h[u]; }
        if (ZERO) {
#pragma unroll
            for (int u = 0; u < G; ++u) hist[base + u] = 0;
        }
    } else {
#pragma unroll
        for (int u = 0; u < G; ++u) h[u] = 0;
    }
    part[tid] = s;
    __syncthreads();

    if (tid < 64) {
        uint32_t gs = 0;
#pragma unroll
        for (int u = 0; u < 8; ++u) gs += part[(tid << 3) + u];
        // suffix scan across 64 lanes: S_l = sum_{l' >= l} gs_{l'}
        uint32_t S = gs;
#pragma unroll
        for (int off = 1; off < 64; off <<= 1) {
            uint32_t v = __shfl_down(S, off, 64);
            if (tid + off < 64) S += v;
        }
        gsufx[tid] = S;
        if (tid == 0) gsufx[64] = 0;
    }
    __syncthreads();

    const int g8 = tid >> 3;
    uint32_t A = gsufx[g8 + 1];                 // count strictly above this group of 8 threads
    for (int t2 = tid + 1; t2 < ((g8 + 1) << 3); ++t2) A += part[t2];
    // A = count of elements in buckets strictly above this thread's buckets
    if (base < NB && A < rem && A + s >= rem) {
        uint32_t acc = 0, bsel = (uint32_t)base, r = 1;
#pragma unroll
        for (int u = G - 1; u >= 0; --u) {
            if (A + acc + h[u] >= rem) { bsel = (uint32_t)(base + u); r = rem - A - acc; break; }
            acc += h[u];
        }
        misc[0] = bsel;
        misc[1] = r;
    }
    __syncthreads();
    *bucket_out = misc[0];
    *rem_out    = misc[1];
}

__global__ void __launch_bounds__(NT, 8)   // 8 waves/EU -> 4 blocks/CU resident
rtdetr_post_kernel(const float* __restrict__ logits, const float* __restrict__ pboxes,
                   const float* __restrict__ sizes, float* __restrict__ out) {
    __shared__ uint64_t sel[SELCAP];
    __shared__ uint32_t hist[4096];
    __shared__ uint32_t part[NT];
    __shared__ uint32_t gsufx[65];
    __shared__ uint32_t misc[4];

    const int tid = threadIdx.x;
    const int b   = blockIdx.x;

    // ---- zero hist + candidate counter ----
    for (int i = tid; i < 4096; i += NT) hist[i] = 0;
    if (tid == 0) misc[2] = 0;

    // keys: order-preserving u32 transform of logit f32 bits
    uint32_t key[NV4 * 4];
    const float4* lg4 = reinterpret_cast<const float4*>(logits + (size_t)b * QC);
#pragma unroll
    for (int k = 0; k < NV4; ++k) {
        const int i4 = tid + (k << 9);
        if (k < NV4 - 1 || tid < TAIL4) {
            float4 v = lg4[i4];
            uint32_t u0 = __float_as_uint(v.x), u1 = __float_as_uint(v.y);
            uint32_t u2 = __float_as_uint(v.z), u3 = __float_as_uint(v.w);
            key[4 * k + 0] = (u0 & 0x80000000u) ? ~u0 : (u0 | 0x80000000u);
            key[4 * k + 1] = (u1 & 0x80000000u) ? ~u1 : (u1 | 0x80000000u);
            key[4 * k + 2] = (u2 & 0x80000000u) ? ~u2 : (u2 | 0x80000000u);
            key[4 * k + 3] = (u3 & 0x80000000u) ? ~u3 : (u3 | 0x80000000u);
        } else {
            key[4 * k + 0] = 0; key[4 * k + 1] = 0; key[4 * k + 2] = 0; key[4 * k + 3] = 0;
        }
    }
    __syncthreads();

    // ---- pass A: histogram key[31:20] (4096 buckets) ----
#pragma unroll
    for (int k = 0; k < NV4; ++k) {
        if (k < NV4 - 1 || tid < TAIL4) {
#pragma unroll
            for (int c = 0; c < 4; ++c)
                atomicAdd(&hist[key[4 * k + c] >> 20], 1u);
        }
    }
    __syncthreads();
    uint32_t b1, r1;
    pick<4096, true>(hist, part, gsufx, misc, tid, RSEL, &b1, &r1);

    // ---- pass B: histogram key[19:8] among bucket-b1 matches (hist pre-zeroed) ----
#pragma unroll
    for (int k = 0; k < NV4; ++k) {
#pragma unroll
        for (int c = 0; c < 4; ++c) {
            uint32_t v = key[4 * k + c];
            if ((v >> 20) == b1) atomicAdd(&hist[(v >> 8) & 0xFFFu], 1u);
        }
    }
    __syncthreads();
    uint32_t b2, r2;
    pick<4096, true>(hist, part, gsufx, misc, tid, r1, &b2, &r2);
    const uint32_t p24 = (b1 << 12) | b2;

    // ---- pass C: histogram key[7:0] among 24-bit prefix matches ----
#pragma unroll
    for (int k = 0; k < NV4; ++k) {
#pragma unroll
        for (int c = 0; c < 4; ++c) {
            uint32_t v = key[4 * k + c];
            if ((v >> 8) == p24) atomicAdd(&hist[v & 0xFFu], 1u);
        }
    }
    __syncthreads();
    uint32_t b3, r3;
    pick<256, false>(hist, part, gsufx, misc, tid, r2, &b3, &r3);
    (void)r3;
    const uint32_t T = (p24 << 8) | b3;  // exact bits of the rank-RSEL logit key

    // ---- collect all elements with key >= T (n in [RSEL, RSEL+dups]) ----
#pragma unroll
    for (int k = 0; k < NV4; ++k) {
#pragma unroll
        for (int c = 0; c < 4; ++c) {
            uint32_t v = key[4 * k + c];
            if (v >= T) {
                uint32_t pos = atomicAdd(&misc[2], 1u);
                uint32_t idx = 4u * (uint32_t)(tid + (k << 9)) + (uint32_t)c;
                if (pos < SELCAP)
                    sel[pos] = ((uint64_t)v << 32) | (uint64_t)(0xFFFFFFFFu - idx);
            }
        }
    }
    __syncthreads();
    const uint32_t cnt = misc[2];
    const uint32_t n = cnt > SELCAP ? SELCAP : cnt;

    // ---- sigmoid only for candidates; rebuild key as (score_bits, ~idx) ----
    uint64_t mykey = 0;
    if ((uint32_t)tid < n) {
        uint64_t e = sel[tid];
        uint32_t lk = (uint32_t)(e >> 32);
        uint32_t bits = (lk & 0x80000000u) ? (lk & 0x7FFFFFFFu) : ~lk;
        float x = __uint_as_float(bits);
        float sc = 1.0f / (1.0f + expf(-x));
        mykey = ((uint64_t)__float_as_uint(sc) << 32) | (uint64_t)(uint32_t)e;
        sel[tid] = mykey;
    }
    __syncthreads();

    // ---- exact rank by (score desc, idx asc): broadcast count, no barriers ----
    if ((uint32_t)tid < n) {
        uint32_t rank = 0;
#pragma unroll 4
        for (uint32_t j = 0; j < n; ++j)
            rank += (sel[j] > mykey) ? 1u : 0u;
        if (rank < TOPK) {
            uint32_t idx = 0xFFFFFFFFu - (uint32_t)(mykey & 0xFFFFFFFFull);
            uint32_t lab = idx % NC;
            uint32_t q   = idx / NC;
            float4 bx = reinterpret_cast<const float4*>(pboxes)[(size_t)b * NQ + q];
            float sw = sizes[2 * b + 0];
            float sh = sizes[2 * b + 1];
            float hw = 0.5f * bx.z, hh = 0.5f * bx.w;
            float4 o;
            o.x = (bx.x - hw) * sw;
            o.y = (bx.y - hh) * sh;
            o.z = (bx.x + hw) * sw;
            o.w = (bx.y + hh) * sh;
            out[(size_t)b * TOPK + rank] = (float)lab;                                   // labels
            reinterpret_cast<float4*>(out + (size_t)NBATCH * TOPK)[(size_t)b * TOPK + rank] = o; // boxes
            out[(size_t)NBATCH * TOPK * 5 + (size_t)b * TOPK + rank] =
                __uint_as_float((uint32_t)(mykey >> 32));                                // scores
        }
    }
}

extern "C" void kernel_launch(void* const* d_in, const int* in_sizes, int n_in,
                              void* d_out, int out_size, void* d_ws, size_t ws_size,
                              hipStream_t stream) {
    const float* logits = (const float*)d_in[0];   // [1024,300,80] f32
    const float* pboxes = (const float*)d_in[1];   // [1024,300,4]  f32
    const float* sizes  = (const float*)d_in[2];   // [1024,2]      f32
    float* out = (float*)d_out;                    // labels | boxes | scores (flat f32)

    hipLaunchKernelGGL(rtdetr_post_kernel, dim3(NBATCH), dim3(NT), 0, stream,
                       logits, pboxes, sizes, out);
}

// Round 4
// 58.117 us; speedup vs baseline: 2.4505x; 2.4505x over previous
//
#include <hip/hip_runtime.h>
#include <stdint.h>

// Problem constants
#define NBATCH 1024
#define NQ 300
#define NC 80
#define QC 24000       // NQ * NC floats per batch
#define NF4 6000       // QC / 4
#define TOPK 300
#define RSEL 384u      // select margin over 300 (covers sigmoid score-tie classes)
#define NT 256         // threads per block
#define NB1 2048       // coarse histogram buckets (key bits [31:21])
#define SH1 21
#define SH2 13         // refine bucket = (key >> 13) & 0xFF
#define SELCAP 768

// ---------------------------------------------------------------------------
// pick<NB,ZERO>: hist[NB] finalized -> find bucket (from the top) containing
// the rem-th largest element + residual count inside it. If ZERO, re-zeroes
// hist (thread-owned buckets, race-free under existing barriers). 3 barriers.
// ---------------------------------------------------------------------------
template<int NB, bool ZERO>
__device__ __forceinline__ void pick(uint32_t* __restrict__ hist,
                                     uint32_t* __restrict__ part,
                                     uint32_t* __restrict__ gsufx,
                                     uint32_t* __restrict__ misc,
                                     int tid, uint32_t rem,
                                     uint32_t* bucket_out, uint32_t* rem_out) {
    constexpr int G = (NB >= NT) ? (NB / NT) : 1;
    const int base = tid * G;
    uint32_t h[G];
    uint32_t s = 0;
#pragma unroll
    for (int u = 0; u < G; ++u) { h[u] = hist[base + u]; s += h[u]; }
    if (ZERO) {
#pragma unroll
        for (int u = 0; u < G; ++u) hist[base + u] = 0;
    }
    part[tid] = s;
    __syncthreads();

    if (tid < 32) {                       // 32 groups of 8 threads
        uint32_t gs = 0;
#pragma unroll
        for (int u = 0; u < 8; ++u) gs += part[(tid << 3) + u];
        uint32_t S = gs;                  // suffix scan over 32 lanes
#pragma unroll
        for (int off = 1; off < 32; off <<= 1) {
            uint32_t v = __shfl_down(S, off, 64);
            if (tid + off < 32) S += v;
        }
        gsufx[tid] = S;
        if (tid == 0) gsufx[32] = 0;
    }
    __syncthreads();

    const int g8 = tid >> 3;
    uint32_t A = gsufx[g8 + 1];           // elements strictly above this 8-thread group
    for (int t2 = tid + 1; t2 < ((g8 + 1) << 3); ++t2) A += part[t2];
    // A = elements in buckets strictly above this thread's buckets
    if (A < rem && A + s >= rem) {
        uint32_t acc = 0, bsel = (uint32_t)base, r = 1;
#pragma unroll
        for (int u = G - 1; u >= 0; --u) {
            if (A + acc + h[u] >= rem) { bsel = (uint32_t)(base + u); r = rem - A - acc; break; }
            acc += h[u];
        }
        misc[0] = bsel;
        misc[1] = r;
    }
    __syncthreads();
    *bucket_out = misc[0];
    *rem_out    = misc[1];
}

__device__ __forceinline__ uint32_t xform(uint32_t u) {
    // order-preserving f32-bits -> u32 key
    return (u & 0x80000000u) ? ~u : (u | 0x80000000u);
}

__global__ void __launch_bounds__(NT, 8)   // 8 blocks/CU target, ~15.5KB LDS each
rtdetr_post_kernel(const float* __restrict__ logits, const float* __restrict__ pboxes,
                   const float* __restrict__ sizes, float* __restrict__ out) {
    __shared__ __align__(16) uint32_t hist[NB1];   // 8KB; [0:256) reused as refine hist
    __shared__ uint64_t sel[SELCAP];               // 6KB
    __shared__ uint32_t part[NT];                  // 1KB
    __shared__ uint32_t gsufx[34];
    __shared__ uint32_t misc[4];
    uint64_t* sel2 = reinterpret_cast<uint64_t*>(&hist[512]);  // 768 u64 overlay (6KB)

    const int tid = threadIdx.x;
    const int b   = blockIdx.x;
    const float4* lg4 = reinterpret_cast<const float4*>(logits + (size_t)b * QC);

    for (int i = tid; i < NB1; i += NT) hist[i] = 0;
    if (tid == 0) { misc[2] = 0; misc[3] = 0; }
    __syncthreads();

    // ---- pass 1: coarse 11-bit histogram over logit keys ----
    for (int i4 = tid; i4 < NF4; i4 += NT) {
        float4 v = lg4[i4];
        atomicAdd(&hist[xform(__float_as_uint(v.x)) >> SH1], 1u);
        atomicAdd(&hist[xform(__float_as_uint(v.y)) >> SH1], 1u);
        atomicAdd(&hist[xform(__float_as_uint(v.z)) >> SH1], 1u);
        atomicAdd(&hist[xform(__float_as_uint(v.w)) >> SH1], 1u);
    }
    __syncthreads();
    uint32_t b1, r1;
    pick<NB1, true>(hist, part, gsufx, misc, tid, RSEL, &b1, &r1);   // also re-zeroes hist

    // ---- pass 2: re-read; collect candidates >= bucket floor; refine hist on b1 ----
    for (int i4 = tid; i4 < NF4; i4 += NT) {
        float4 v = lg4[i4];
        uint32_t kk[4] = { xform(__float_as_uint(v.x)), xform(__float_as_uint(v.y)),
                           xform(__float_as_uint(v.z)), xform(__float_as_uint(v.w)) };
#pragma unroll
        for (int c = 0; c < 4; ++c) {
            uint32_t k = kk[c];
            uint32_t bk = k >> SH1;
            if (bk >= b1) {
                uint32_t pos = atomicAdd(&misc[2], 1u);
                uint32_t idx = 4u * (uint32_t)i4 + (uint32_t)c;
                if (pos < SELCAP)
                    sel[pos] = ((uint64_t)k << 32) | (uint64_t)(0xFFFFFFFFu - idx);
                if (bk == b1) atomicAdd(&hist[(k >> SH2) & 0xFFu], 1u);
            }
        }
    }
    __syncthreads();
    uint32_t t2, r2;
    pick<256, false>(hist, part, gsufx, misc, tid, r1, &t2, &r2);
    (void)r2;
    const uint32_t T2 = (b1 << SH1) | (t2 << SH2);   // 19-bit refined threshold
    const uint32_t cnt = misc[2];
    const uint32_t n = cnt > SELCAP ? SELCAP : cnt;

    // ---- compact finalists (key >= T2): sigmoid -> (score_bits, ~idx) keys ----
    for (uint32_t i = tid; i < n; i += NT) {
        uint64_t e = sel[i];
        uint32_t k = (uint32_t)(e >> 32);
        if (k >= T2) {
            uint32_t bits = (k & 0x80000000u) ? (k & 0x7FFFFFFFu) : ~k;
            float x  = __uint_as_float(bits);
            float sc = 1.0f / (1.0f + expf(-x));
            uint32_t pos = atomicAdd(&misc[3], 1u);
            if (pos < SELCAP)
                sel2[pos] = ((uint64_t)__float_as_uint(sc) << 32) | (uint64_t)(uint32_t)e;
        }
    }
    __syncthreads();
    const uint32_t m3 = misc[3];
    const uint32_t n2 = m3 > SELCAP ? SELCAP : m3;   // ~386 finalists

    // ---- exact rank by (score desc, idx asc): broadcast count, barrier-free ----
    for (uint32_t i = tid; i < n2; i += NT) {
        uint64_t my = sel2[i];
        uint32_t rank = 0;
        for (uint32_t j = 0; j < n2; ++j)
            rank += (sel2[j] > my) ? 1u : 0u;
        if (rank < TOPK) {
            uint32_t idx = 0xFFFFFFFFu - (uint32_t)(my & 0xFFFFFFFFull);
            uint32_t lab = idx % NC;
            uint32_t q   = idx / NC;
            float4 bx = reinterpret_cast<const float4*>(pboxes)[(size_t)b * NQ + q];
            float sw = sizes[2 * b + 0];
            float sh = sizes[2 * b + 1];
            float hw = 0.5f * bx.z, hh = 0.5f * bx.w;
            float4 o;
            o.x = (bx.x - hw) * sw;
            o.y = (bx.y - hh) * sh;
            o.z = (bx.x + hw) * sw;
            o.w = (bx.y + hh) * sh;
            out[(size_t)b * TOPK + rank] = (float)lab;                                    // labels
            reinterpret_cast<float4*>(out + (size_t)NBATCH * TOPK)[(size_t)b * TOPK + rank] = o; // boxes
            out[(size_t)NBATCH * TOPK * 5 + (size_t)b * TOPK + rank] =
                __uint_as_float((uint32_t)(my >> 32));                                    // scores
        }
    }
}

extern "C" void kernel_launch(void* const* d_in, const int* in_sizes, int n_in,
                              void* d_out, int out_size, void* d_ws, size_t ws_size,
                              hipStream_t stream) {
    const float* logits = (const float*)d_in[0];   // [1024,300,80] f32
    const float* pboxes = (const float*)d_in[1];   // [1024,300,4]  f32
    const float* sizes  = (const float*)d_in[2];   // [1024,2]      f32
    float* out = (float*)d_out;                    // labels | boxes | scores (flat f32)

    hipLaunchKernelGGL(rtdetr_post_kernel, dim3(NBATCH), dim3(NT), 0, stream,
                       logits, pboxes, sizes, out);
}

// Round 5
// 50.612 us; speedup vs baseline: 2.8139x; 1.1483x over previous
//
#include <hip/hip_runtime.h>
#include <stdint.h>

// Problem constants
#define NBATCH 1024
#define NQ 300
#define NC 80
#define QC 24000       // NQ * NC floats per batch
#define NF4 6000       // QC / 4
#define TOPK 300
#define RSEL 384u      // select margin over 300 (covers sigmoid score-tie classes)
#define NT 512         // threads per block (8 waves)
#define NB1 2048       // coarse histogram buckets (key bits [31:21])
#define SH1 21
#define SH2 13         // refine bucket = (key >> 13) & 0xFF
#define SELCAP 768
#define TAIL 368       // threads with a valid 12th float4 (6000 - 11*512)

// order-preserving f32-bits -> u32 key (branchless)
__device__ __forceinline__ uint32_t xform(uint32_t u) {
    return u ^ (uint32_t)(((int32_t)u >> 31) | 0x80000000);
}

// ---------------------------------------------------------------------------
// pick<NB,ZERO>: hist[NB] finalized -> find bucket (from the top) containing
// the rem-th largest element + residual count inside it. If ZERO, re-zeroes
// hist (thread-owned buckets, race-free under existing barriers). 3 barriers.
// ---------------------------------------------------------------------------
template<int NB, bool ZERO>
__device__ __forceinline__ void pick(uint32_t* __restrict__ hist,
                                     uint32_t* __restrict__ part,
                                     uint32_t* __restrict__ gsufx,
                                     uint32_t* __restrict__ misc,
                                     int tid, uint32_t rem,
                                     uint32_t* bucket_out, uint32_t* rem_out) {
    constexpr int G = (NB >= NT) ? (NB / NT) : 1;
    const int base = tid * G;
    uint32_t h[G];
    uint32_t s = 0;
    if (base < NB) {
#pragma unroll
        for (int u = 0; u < G; ++u) { h[u] = hist[base + u]; s += h[u]; }
        if (ZERO) {
#pragma unroll
            for (int u = 0; u < G; ++u) hist[base + u] = 0;
        }
    } else {
#pragma unroll
        for (int u = 0; u < G; ++u) h[u] = 0;
    }
    part[tid] = s;
    __syncthreads();

    if (tid < 64) {                        // 64 groups of 8 threads
        uint32_t gs = 0;
#pragma unroll
        for (int u = 0; u < 8; ++u) gs += part[(tid << 3) + u];
        uint32_t S = gs;                   // suffix scan across 64 lanes
#pragma unroll
        for (int off = 1; off < 64; off <<= 1) {
            uint32_t v = __shfl_down(S, off, 64);
            if (tid + off < 64) S += v;
        }
        gsufx[tid] = S;
        if (tid == 0) gsufx[64] = 0;
    }
    __syncthreads();

    const int g8 = tid >> 3;
    uint32_t A = gsufx[g8 + 1];            // elements strictly above this 8-thread group
    for (int t2 = tid + 1; t2 < ((g8 + 1) << 3); ++t2) A += part[t2];
    // A = elements in buckets strictly above this thread's buckets
    if (base < NB && A < rem && A + s >= rem) {
        uint32_t acc = 0, bsel = (uint32_t)base, r = 1;
#pragma unroll
        for (int u = G - 1; u >= 0; --u) {
            if (A + acc + h[u] >= rem) { bsel = (uint32_t)(base + u); r = rem - A - acc; break; }
            acc += h[u];
        }
        misc[0] = bsel;
        misc[1] = r;
    }
    __syncthreads();
    *bucket_out = misc[0];
    *rem_out    = misc[1];
}

__global__ void __launch_bounds__(NT, 6)
rtdetr_post_kernel(const float* __restrict__ logits, const float* __restrict__ pboxes,
                   const float* __restrict__ sizes, float* __restrict__ out) {
    __shared__ __align__(16) uint32_t hist[NB1];   // 8KB; [0:256) reused as refine hist
    __shared__ uint64_t sel[SELCAP];               // 6KB
    __shared__ uint32_t part[NT];                  // 2KB
    __shared__ uint32_t gsufx[65];
    __shared__ uint32_t misc[4];
    uint64_t* sel2 = reinterpret_cast<uint64_t*>(&hist[512]);  // 768 u64 overlay (6KB)

    const int tid = threadIdx.x;
    const int b   = blockIdx.x;
    const float4* lg4 = reinterpret_cast<const float4*>(logits + (size_t)b * QC);

    for (int i = tid; i < NB1; i += NT) hist[i] = 0;
    if (tid == 0) { misc[2] = 0; misc[3] = 0; }
    __syncthreads();

    // ---- pass 1: coarse 11-bit histogram; 6-deep load batching for MLP ----
    {
        float4 va[6];
#pragma unroll
        for (int k = 0; k < 6; ++k) va[k] = lg4[tid + (k << 9)];
#pragma unroll
        for (int k = 0; k < 6; ++k) {
            atomicAdd(&hist[xform(__float_as_uint(va[k].x)) >> SH1], 1u);
            atomicAdd(&hist[xform(__float_as_uint(va[k].y)) >> SH1], 1u);
            atomicAdd(&hist[xform(__float_as_uint(va[k].z)) >> SH1], 1u);
            atomicAdd(&hist[xform(__float_as_uint(va[k].w)) >> SH1], 1u);
        }
#pragma unroll
        for (int k = 0; k < 6; ++k)
            if (k < 5 || tid < TAIL) va[k] = lg4[tid + ((k + 6) << 9)];
#pragma unroll
        for (int k = 0; k < 6; ++k) {
            if (k < 5 || tid < TAIL) {
                atomicAdd(&hist[xform(__float_as_uint(va[k].x)) >> SH1], 1u);
                atomicAdd(&hist[xform(__float_as_uint(va[k].y)) >> SH1], 1u);
                atomicAdd(&hist[xform(__float_as_uint(va[k].z)) >> SH1], 1u);
                atomicAdd(&hist[xform(__float_as_uint(va[k].w)) >> SH1], 1u);
            }
        }
    }
    __syncthreads();
    uint32_t b1, r1;
    pick<NB1, true>(hist, part, gsufx, misc, tid, RSEL, &b1, &r1);  // also re-zeroes hist

    // ---- pass 2: re-read (L3-hot); collect candidates >= bucket floor;
    //      refine 8-bit hist over bucket-b1 members ----
    {
        float4 va[6];
#pragma unroll
        for (int k = 0; k < 6; ++k) va[k] = lg4[tid + (k << 9)];
#pragma unroll
        for (int k = 0; k < 6; ++k) {
            const uint32_t i4 = (uint32_t)(tid + (k << 9));
            const uint32_t kk[4] = { xform(__float_as_uint(va[k].x)), xform(__float_as_uint(va[k].y)),
                                     xform(__float_as_uint(va[k].z)), xform(__float_as_uint(va[k].w)) };
#pragma unroll
            for (int c = 0; c < 4; ++c) {
                uint32_t kx = kk[c];
                uint32_t bk = kx >> SH1;
                if (bk >= b1) {
                    uint32_t pos = atomicAdd(&misc[2], 1u);
                    uint32_t idx = 4u * i4 + (uint32_t)c;
                    if (pos < SELCAP)
                        sel[pos] = ((uint64_t)kx << 32) | (uint64_t)(0xFFFFFFFFu - idx);
                    if (bk == b1) atomicAdd(&hist[(kx >> SH2) & 0xFFu], 1u);
                }
            }
        }
#pragma unroll
        for (int k = 0; k < 6; ++k)
            if (k < 5 || tid < TAIL) va[k] = lg4[tid + ((k + 6) << 9)];
#pragma unroll
        for (int k = 0; k < 6; ++k) {
            if (k < 5 || tid < TAIL) {
                const uint32_t i4 = (uint32_t)(tid + ((k + 6) << 9));
                const uint32_t kk[4] = { xform(__float_as_uint(va[k].x)), xform(__float_as_uint(va[k].y)),
                                         xform(__float_as_uint(va[k].z)), xform(__float_as_uint(va[k].w)) };
#pragma unroll
                for (int c = 0; c < 4; ++c) {
                    uint32_t kx = kk[c];
                    uint32_t bk = kx >> SH1;
                    if (bk >= b1) {
                        uint32_t pos = atomicAdd(&misc[2], 1u);
                        uint32_t idx = 4u * i4 + (uint32_t)c;
                        if (pos < SELCAP)
                            sel[pos] = ((uint64_t)kx << 32) | (uint64_t)(0xFFFFFFFFu - idx);
                        if (bk == b1) atomicAdd(&hist[(kx >> SH2) & 0xFFu], 1u);
                    }
                }
            }
        }
    }
    __syncthreads();
    uint32_t t2, r2;
    pick<256, false>(hist, part, gsufx, misc, tid, r1, &t2, &r2);
    (void)r2;
    const uint32_t T2 = (b1 << SH1) | (t2 << SH2);   // 19-bit refined threshold
    const uint32_t cnt = misc[2];
    const uint32_t n = cnt > SELCAP ? SELCAP : cnt;

    // ---- compact finalists (key >= T2): sigmoid -> (score_bits, ~idx) keys ----
    for (uint32_t i = tid; i < n; i += NT) {
        uint64_t e = sel[i];
        uint32_t k = (uint32_t)(e >> 32);
        if (k >= T2) {
            uint32_t bits = (k & 0x80000000u) ? (k & 0x7FFFFFFFu) : ~k;
            float x  = __uint_as_float(bits);
            float sc = 1.0f / (1.0f + expf(-x));
            uint32_t pos = atomicAdd(&misc[3], 1u);
            if (pos < SELCAP)
                sel2[pos] = ((uint64_t)__float_as_uint(sc) << 32) | (uint64_t)(uint32_t)e;
        }
    }
    __syncthreads();
    const uint32_t m3 = misc[3];
    const uint32_t n2 = m3 > SELCAP ? SELCAP : m3;   // ~386 finalists

    // ---- exact rank by (score desc, idx asc): broadcast count, barrier-free ----
    for (uint32_t i = tid; i < n2; i += NT) {
        uint64_t my = sel2[i];
        uint32_t rank = 0;
        for (uint32_t j = 0; j < n2; ++j)
            rank += (sel2[j] > my) ? 1u : 0u;
        if (rank < TOPK) {
            uint32_t idx = 0xFFFFFFFFu - (uint32_t)(my & 0xFFFFFFFFull);
            uint32_t lab = idx % NC;
            uint32_t q   = idx / NC;
            float4 bx = reinterpret_cast<const float4*>(pboxes)[(size_t)b * NQ + q];
            float sw = sizes[2 * b + 0];
            float sh = sizes[2 * b + 1];
            float hw = 0.5f * bx.z, hh = 0.5f * bx.w;
            float4 o;
            o.x = (bx.x - hw) * sw;
            o.y = (bx.y - hh) * sh;
            o.z = (bx.x + hw) * sw;
            o.w = (bx.y + hh) * sh;
            out[(size_t)b * TOPK + rank] = (float)lab;                                    // labels
            reinterpret_cast<float4*>(out + (size_t)NBATCH * TOPK)[(size_t)b * TOPK + rank] = o; // boxes
            out[(size_t)NBATCH * TOPK * 5 + (size_t)b * TOPK + rank] =
                __uint_as_float((uint32_t)(my >> 32));                                    // scores
        }
    }
}

extern "C" void kernel_launch(void* const* d_in, const int* in_sizes, int n_in,
                              void* d_out, int out_size, void* d_ws, size_t ws_size,
                              hipStream_t stream) {
    const float* logits = (const float*)d_in[0];   // [1024,300,80] f32
    const float* pboxes = (const float*)d_in[1];   // [1024,300,4]  f32
    const float* sizes  = (const float*)d_in[2];   // [1024,2]      f32
    float* out = (float*)d_out;                    // labels | boxes | scores (flat f32)

    hipLaunchKernelGGL(rtdetr_post_kernel, dim3(NBATCH), dim3(NT), 0, stream,
                       logits, pboxes, sizes, out);
}

// Round 6
// 41.775 us; speedup vs baseline: 3.4091x; 1.2115x over previous
//
#include <hip/hip_runtime.h>
#include <stdint.h>

// Problem constants
#define NBATCH 1024
#define NQ 300
#define NC 80
#define QC 24000       // NQ * NC floats per batch
#define NF4 6000       // QC / 4
#define TOPK 300
#define RSEL 384u      // select margin over 300 (covers sigmoid score-tie classes)
#define NT 512         // threads per block (8 waves)
#define NB1 2048       // coarse histogram buckets (key bits [31:21])
#define SH1 21
#define SH2 13         // refine bucket = (key >> 13) & 0xFF
#define SELCAP 2048    // candidate buffer (expected ~1600 prefilter hits)
#define FINCAP 768     // finalist buffer (expected ~390)
#define TAIL 368       // threads with a valid 12th float4 (6000 - 11*512)
#define PREFKEY 0xBFC00000u  // xform(bits(1.5f)): candidate iff logit >= 1.5

// order-preserving f32-bits -> u32 key (branchless)
__device__ __forceinline__ uint32_t xform(uint32_t u) {
    return u ^ (uint32_t)(((int32_t)u >> 31) | 0x80000000);
}

// ---------------------------------------------------------------------------
// pick<NB,ZERO>: hist[NB] finalized -> find bucket (from the top) containing
// the rem-th largest element + residual count inside it. If ZERO, re-zeroes
// hist (thread-owned buckets, race-free under existing barriers). 3 barriers.
// ---------------------------------------------------------------------------
template<int NB, bool ZERO>
__device__ __forceinline__ void pick(uint32_t* __restrict__ hist,
                                     uint32_t* __restrict__ part,
                                     uint32_t* __restrict__ gsufx,
                                     uint32_t* __restrict__ misc,
                                     int tid, uint32_t rem,
                                     uint32_t* bucket_out, uint32_t* rem_out) {
    constexpr int G = (NB >= NT) ? (NB / NT) : 1;
    const int base = tid * G;
    uint32_t h[G];
    uint32_t s = 0;
    if (base < NB) {
#pragma unroll
        for (int u = 0; u < G; ++u) { h[u] = hist[base + u]; s += h[u]; }
        if (ZERO) {
#pragma unroll
            for (int u = 0; u < G; ++u) hist[base + u] = 0;
        }
    } else {
#pragma unroll
        for (int u = 0; u < G; ++u) h[u] = 0;
    }
    part[tid] = s;
    __syncthreads();

    if (tid < 64) {                        // 64 groups of 8 threads
        uint32_t gs = 0;
#pragma unroll
        for (int u = 0; u < 8; ++u) gs += part[(tid << 3) + u];
        uint32_t S = gs;                   // suffix scan across 64 lanes
#pragma unroll
        for (int off = 1; off < 64; off <<= 1) {
            uint32_t v = __shfl_down(S, off, 64);
            if (tid + off < 64) S += v;
        }
        gsufx[tid] = S;
        if (tid == 0) gsufx[64] = 0;
    }
    __syncthreads();

    const int g8 = tid >> 3;
    uint32_t A = gsufx[g8 + 1];            // elements strictly above this 8-thread group
    for (int t2 = tid + 1; t2 < ((g8 + 1) << 3); ++t2) A += part[t2];
    if (base < NB && A < rem && A + s >= rem) {
        uint32_t acc = 0, bsel = (uint32_t)base, r = 1;
#pragma unroll
        for (int u = G - 1; u >= 0; --u) {
            if (A + acc + h[u] >= rem) { bsel = (uint32_t)(base + u); r = rem - A - acc; break; }
            acc += h[u];
        }
        misc[0] = bsel;
        misc[1] = r;
    }
    __syncthreads();
    *bucket_out = misc[0];
    *rem_out    = misc[1];
}

__global__ void __launch_bounds__(NT, 6)
rtdetr_post_kernel(const float* __restrict__ logits, const float* __restrict__ pboxes,
                   const float* __restrict__ sizes, float* __restrict__ out) {
    __shared__ __align__(16) uint32_t hist[NB1];   // 8KB; [0:256) reused as refine hist
    __shared__ uint64_t sel[SELCAP];               // 16KB candidates
    __shared__ uint32_t part[NT];                  // 2KB
    __shared__ uint32_t gsufx[65];
    __shared__ uint32_t misc[4];
    uint64_t* sel2 = reinterpret_cast<uint64_t*>(&hist[512]);  // 768 u64 overlay (6KB)

    const int tid = threadIdx.x;
    const int b   = blockIdx.x;
    const float4* lg4 = reinterpret_cast<const float4*>(logits + (size_t)b * QC);

    for (int i = tid; i < NB1; i += NT) hist[i] = 0;
    if (tid == 0) { misc[2] = 0; misc[3] = 0; }
    __syncthreads();

    // ---- pass 1: pure stream + prefilter collect (no per-element atomics) ----
    {
        float4 va[6];
#pragma unroll
        for (int k = 0; k < 6; ++k) va[k] = lg4[tid + (k << 9)];
#pragma unroll
        for (int k = 0; k < 6; ++k) {
            uint32_t k0 = xform(__float_as_uint(va[k].x));
            uint32_t k1 = xform(__float_as_uint(va[k].y));
            uint32_t k2 = xform(__float_as_uint(va[k].z));
            uint32_t k3 = xform(__float_as_uint(va[k].w));
            if (max(max(k0, k1), max(k2, k3)) >= PREFKEY) {
                const uint32_t i4 = (uint32_t)(tid + (k << 9));
                uint32_t kk[4] = { k0, k1, k2, k3 };
#pragma unroll
                for (int c = 0; c < 4; ++c) {
                    if (kk[c] >= PREFKEY) {
                        uint32_t pos = atomicAdd(&misc[2], 1u);
                        uint32_t idx = 4u * i4 + (uint32_t)c;
                        if (pos < SELCAP)
                            sel[pos] = ((uint64_t)kk[c] << 32) | (uint64_t)(0xFFFFFFFFu - idx);
                    }
                }
            }
        }
#pragma unroll
        for (int k = 0; k < 6; ++k)
            if (k < 5 || tid < TAIL) va[k] = lg4[tid + ((k + 6) << 9)];
#pragma unroll
        for (int k = 0; k < 6; ++k) {
            if (k < 5 || tid < TAIL) {
                uint32_t k0 = xform(__float_as_uint(va[k].x));
                uint32_t k1 = xform(__float_as_uint(va[k].y));
                uint32_t k2 = xform(__float_as_uint(va[k].z));
                uint32_t k3 = xform(__float_as_uint(va[k].w));
                if (max(max(k0, k1), max(k2, k3)) >= PREFKEY) {
                    const uint32_t i4 = (uint32_t)(tid + ((k + 6) << 9));
                    uint32_t kk[4] = { k0, k1, k2, k3 };
#pragma unroll
                    for (int c = 0; c < 4; ++c) {
                        if (kk[c] >= PREFKEY) {
                            uint32_t pos = atomicAdd(&misc[2], 1u);
                            uint32_t idx = 4u * i4 + (uint32_t)c;
                            if (pos < SELCAP)
                                sel[pos] = ((uint64_t)kk[c] << 32) | (uint64_t)(0xFFFFFFFFu - idx);
                        }
                    }
                }
            }
        }
    }
    __syncthreads();
    uint32_t cnt = misc[2];

    uint32_t T2;     // refined 19-bit threshold (key >= T2 -> finalist)
    uint32_t n;      // valid entries in sel[]

    if (cnt >= RSEL && cnt <= SELCAP) {
        // ======== FAST PATH: select entirely within LDS candidates ========
        n = cnt;
        for (uint32_t i = tid; i < n; i += NT)
            atomicAdd(&hist[(uint32_t)(sel[i] >> 32) >> SH1], 1u);
        __syncthreads();
        uint32_t b1, r1;
        pick<NB1, true>(hist, part, gsufx, misc, tid, RSEL, &b1, &r1);  // re-zeroes hist
        for (uint32_t i = tid; i < n; i += NT) {
            uint32_t k = (uint32_t)(sel[i] >> 32);
            if ((k >> SH1) == b1) atomicAdd(&hist[(k >> SH2) & 0xFFu], 1u);
        }
        __syncthreads();
        uint32_t t2, r2;
        pick<256, false>(hist, part, gsufx, misc, tid, r1, &t2, &r2);
        (void)r2;
        T2 = (b1 << SH1) | (t2 << SH2);
    } else {
        // ======== SLOW PATH (exactness fallback; ~never taken) ========
        // coarse 11-bit histogram over all logits
        for (int i4 = tid; i4 < NF4; i4 += NT) {
            float4 v = lg4[i4];
            atomicAdd(&hist[xform(__float_as_uint(v.x)) >> SH1], 1u);
            atomicAdd(&hist[xform(__float_as_uint(v.y)) >> SH1], 1u);
            atomicAdd(&hist[xform(__float_as_uint(v.z)) >> SH1], 1u);
            atomicAdd(&hist[xform(__float_as_uint(v.w)) >> SH1], 1u);
        }
        __syncthreads();
        uint32_t b1, r1;
        pick<NB1, true>(hist, part, gsufx, misc, tid, RSEL, &b1, &r1);
        if (tid == 0) misc[2] = 0;
        __syncthreads();
        // collect >= bucket floor + refine hist over bucket-b1 members
        for (int i4 = tid; i4 < NF4; i4 += NT) {
            float4 v = lg4[i4];
            uint32_t kk[4] = { xform(__float_as_uint(v.x)), xform(__float_as_uint(v.y)),
                               xform(__float_as_uint(v.z)), xform(__float_as_uint(v.w)) };
#pragma unroll
            for (int c = 0; c < 4; ++c) {
                uint32_t k = kk[c];
                uint32_t bk = k >> SH1;
                if (bk >= b1) {
                    uint32_t pos = atomicAdd(&misc[2], 1u);
                    uint32_t idx = 4u * (uint32_t)i4 + (uint32_t)c;
                    if (pos < SELCAP)
                        sel[pos] = ((uint64_t)k << 32) | (uint64_t)(0xFFFFFFFFu - idx);
                    if (bk == b1) atomicAdd(&hist[(k >> SH2) & 0xFFu], 1u);
                }
            }
        }
        __syncthreads();
        uint32_t t2, r2;
        pick<256, false>(hist, part, gsufx, misc, tid, r1, &t2, &r2);
        (void)r2;
        T2 = (b1 << SH1) | (t2 << SH2);
        uint32_t c2 = misc[2];
        n = c2 > SELCAP ? SELCAP : c2;
    }

    // ---- compact finalists (key >= T2): sigmoid -> (score_bits, ~idx) keys ----
    for (uint32_t i = tid; i < n; i += NT) {
        uint64_t e = sel[i];
        uint32_t k = (uint32_t)(e >> 32);
        if (k >= T2) {
            uint32_t bits = (k & 0x80000000u) ? (k & 0x7FFFFFFFu) : ~k;
            float x  = __uint_as_float(bits);
            float sc = 1.0f / (1.0f + expf(-x));
            uint32_t pos = atomicAdd(&misc[3], 1u);
            if (pos < FINCAP)
                sel2[pos] = ((uint64_t)__float_as_uint(sc) << 32) | (uint64_t)(uint32_t)e;
        }
    }
    __syncthreads();
    const uint32_t m3 = misc[3];
    const uint32_t n2 = m3 > FINCAP ? FINCAP : m3;   // ~390 finalists

    // ---- exact rank by (score desc, idx asc): broadcast count, barrier-free ----
    for (uint32_t i = tid; i < n2; i += NT) {
        uint64_t my = sel2[i];
        uint32_t rank = 0;
        for (uint32_t j = 0; j < n2; ++j)
            rank += (sel2[j] > my) ? 1u : 0u;
        if (rank < TOPK) {
            uint32_t idx = 0xFFFFFFFFu - (uint32_t)(my & 0xFFFFFFFFull);
            uint32_t lab = idx % NC;
            uint32_t q   = idx / NC;
            float4 bx = reinterpret_cast<const float4*>(pboxes)[(size_t)b * NQ + q];
            float sw = sizes[2 * b + 0];
            float sh = sizes[2 * b + 1];
            float hw = 0.5f * bx.z, hh = 0.5f * bx.w;
            float4 o;
            o.x = (bx.x - hw) * sw;
            o.y = (bx.y - hh) * sh;
            o.z = (bx.x + hw) * sw;
            o.w = (bx.y + hh) * sh;
            out[(size_t)b * TOPK + rank] = (float)lab;                                    // labels
            reinterpret_cast<float4*>(out + (size_t)NBATCH * TOPK)[(size_t)b * TOPK + rank] = o; // boxes
            out[(size_t)NBATCH * TOPK * 5 + (size_t)b * TOPK + rank] =
                __uint_as_float((uint32_t)(my >> 32));                                    // scores
        }
    }
}

extern "C" void kernel_launch(void* const* d_in, const int* in_sizes, int n_in,
                              void* d_out, int out_size, void* d_ws, size_t ws_size,
                              hipStream_t stream) {
    const float* logits = (const float*)d_in[0];   // [1024,300,80] f32
    const float* pboxes = (const float*)d_in[1];   // [1024,300,4]  f32
    const float* sizes  = (const float*)d_in[2];   // [1024,2]      f32
    float* out = (float*)d_out;                    // labels | boxes | scores (flat f32)

    hipLaunchKernelGGL(rtdetr_post_kernel, dim3(NBATCH), dim3(NT), 0, stream,
                       logits, pboxes, sizes, out);
}